// Round 3
// baseline (3498.620 us; speedup 1.0000x reference)
//
#include <hip/hip_runtime.h>
#include <hip/hip_bf16.h>

typedef __attribute__((ext_vector_type(8))) short short8;
typedef __attribute__((ext_vector_type(4))) float f32x4;

__device__ __forceinline__ float b2f(unsigned short u) {
    union { unsigned int i; float f; } v; v.i = ((unsigned int)u) << 16; return v.f;
}
__device__ __forceinline__ unsigned short f2b(float f) {
    union { float f; unsigned int i; } v; v.f = f;
    return (unsigned short)((v.i + 0x7FFFu + ((v.i >> 16) & 1u)) >> 16);
}
__device__ __forceinline__ float sig_f(float x) {
    return __builtin_amdgcn_rcpf(1.f + __expf(-x));
}
__device__ __forceinline__ float tanh_f(float x) {
    return 1.f - 2.f * __builtin_amdgcn_rcpf(1.f + __expf(2.f * x));
}
__device__ __forceinline__ void gll16(const void* g, void* lds) {
    __builtin_amdgcn_global_load_lds(
        (const __attribute__((address_space(1))) unsigned int*)g,
        (__attribute__((address_space(3))) unsigned int*)lds, 16, 0, 0);
}

// ---------------------------------------------------------------------------
// Prep: permute+convert token-LSTM weights to bf16 MFMA B-fragment order,
// fold biases, convert attW to fragment order. (unchanged, validated)
// ---------------------------------------------------------------------------
__global__ void k_prep(const float* __restrict__ Wih_f, const float* __restrict__ Whh_f,
                       const float* __restrict__ bih_f, const float* __restrict__ bhh_f,
                       const float* __restrict__ Wih_b, const float* __restrict__ Whh_b,
                       const float* __restrict__ bih_b, const float* __restrict__ bhh_b,
                       const float* __restrict__ attW,
                       short* __restrict__ Wfrag, float* __restrict__ biasp,
                       short* __restrict__ attWfrag)
{
    int idx = blockIdx.x * blockDim.x + threadIdx.x;
    if (idx < 2 * 1024 * 512) {
        int j = idx & 7, lane = (idx >> 3) & 63, b = idx >> 9;
        int gt = b & 3, kk = (b >> 2) & 15, ng = (b >> 6) & 15, dir = b >> 10;
        int u = lane & 15;
        int k = kk * 32 + (lane >> 4) * 8 + j;
        int row = gt * 256 + ng * 16 + u;
        const float* Wih = dir ? Wih_b : Wih_f;
        const float* Whh = dir ? Whh_b : Whh_f;
        float val = (k < 256) ? Wih[row * 256 + k] : Whh[row * 256 + (k - 256)];
        Wfrag[idx] = (short)f2b(val);
    } else if (idx < 2 * 1024 * 512 + 2048) {
        int i = idx - 2 * 1024 * 512;
        int dir = i >> 10, col = i & 1023;
        int ng = col >> 6, rem = col & 63, gt = rem >> 4, u = rem & 15;
        int row = gt * 256 + ng * 16 + u;
        biasp[i] = dir ? (bih_b[row] + bhh_b[row]) : (bih_f[row] + bhh_f[row]);
    } else if (idx < 2 * 1024 * 512 + 2048 + 32768) {
        int o = idx - (2 * 1024 * 512 + 2048);
        int j = o & 7, lane = (o >> 3) & 63, b = o >> 9;
        int kk = b & 7, nt = b >> 3;
        int fa = nt * 16 + (lane & 15);
        int k = kk * 32 + (lane >> 4) * 8 + j;
        attWfrag[o] = (short)f2b(attW[fa * 256 + k]);
    }
}

// convert embedding table to bf16 once (25.6MB)
__global__ void k_prep_emb(const float* __restrict__ emb, unsigned short* __restrict__ emb16)
{
    int idx = blockIdx.x * blockDim.x + threadIdx.x;
    if (idx >= 50000 * 256 / 8) return;
    const float4* s = (const float4*)(emb + (size_t)idx * 8);
    float4 a = s[0], b = s[1];
    short8 v;
    v[0] = (short)f2b(a.x); v[1] = (short)f2b(a.y);
    v[2] = (short)f2b(a.z); v[3] = (short)f2b(a.w);
    v[4] = (short)f2b(b.x); v[5] = (short)f2b(b.y);
    v[6] = (short)f2b(b.z); v[7] = (short)f2b(b.w);
    *(short8*)(emb16 + (size_t)idx * 8) = v;
}

// ---------------------------------------------------------------------------
// Fused token BiLSTM: ONE kernel, all 128 timesteps, recurrence in-block.
// 64 blocks x 1024 threads (16 waves). Block = (dir, 16 sentences).
// dir = bit2 of bid -> same-dir blocks cluster per XCD (L2 holds 1MB W).
// Wave w = gate-group ng (16 units x 4 gates = N-slice of 64).
// x-half: Ax[2][16][512B] double-buffered, staged via global_load_lds
//   (pre-swizzled source chunks; LDS dest linear; read-side XOR matches).
// h-half: Ah[2][16][512B], written by epilogue each step (XOR-swizzled).
// c: registers. One __syncthreads per step.
// ---------------------------------------------------------------------------
__global__ __launch_bounds__(1024, 4) void k_tokf(const int* __restrict__ tokens,
                                                  const unsigned short* __restrict__ emb16,
                                                  const short* __restrict__ Wfrag,
                                                  const float* __restrict__ biasp,
                                                  unsigned short* __restrict__ enc_f,
                                                  unsigned short* __restrict__ enc_b)
{
    __shared__ __align__(16) char Ax[2][16 * 512];
    __shared__ __align__(16) char Ah[2][16 * 512];
    int tid = threadIdx.x;
    int lane = tid & 63, w = tid >> 6;      // w = ng, 0..15
    int bid = blockIdx.x;
    int dir = (bid >> 2) & 1;
    int sg = (bid & 3) | ((bid >> 3) << 2); // 0..31
    int s0 = sg * 16;
    unsigned short* enc = dir ? enc_b : enc_f;

    const short* wbase = Wfrag + ((size_t)((dir * 16 + w) * 16) * 4) * 512 + lane * 8;
    const float* bp = biasp + dir * 1024 + w * 64 + (lane & 15);
    float bi = bp[0], bff = bp[16], bg = bp[32], bo = bp[48];

    int arow = lane & 15;
    int abyteoff = (lane >> 4) * 16;
    int aswz = (arow & 7) << 4;

    // staging (waves 0..7 only): wave w stages rows 2w, 2w+1 with one gll16
    int srow = 2 * (w & 7) + (lane >> 5);
    int schunk = (lane & 31) ^ (srow & 7);
    const int* tokp = tokens + (s0 + srow) * 128;

    float c0 = 0.f, c1 = 0.f, c2 = 0.f, c3 = 0.f;

    // prologue: stage x(0)
    if (w < 8) {
        int tcol0 = dir ? 127 : 0;
        int tok = tokp[tcol0];
        gll16(emb16 + (size_t)tok * 256 + schunk * 8, (char*)Ax[0] + 2 * w * 512);
    }
    __syncthreads();

    int u = w * 16 + (lane & 15);
    for (int t = 0; t < 128; ++t) {
        int cur = t & 1;
        // stage x(t+1) into the other buffer (off critical path)
        if (t < 127 && w < 8) {
            int tcol = dir ? (126 - t) : (t + 1);
            int tok = tokp[tcol];
            gll16(emb16 + (size_t)tok * 256 + schunk * 8,
                  (char*)Ax[cur ^ 1] + 2 * w * 512);
        }
        f32x4 acc0 = {0.f, 0.f, 0.f, 0.f};
        f32x4 acc1 = {0.f, 0.f, 0.f, 0.f};
        f32x4 acc2 = {0.f, 0.f, 0.f, 0.f};
        f32x4 acc3 = {0.f, 0.f, 0.f, 0.f};
        const char* axb = (const char*)Ax[cur];
        const char* ahb = (const char*)Ah[cur];
        #pragma unroll
        for (int kk = 0; kk < 8; ++kk) {
            int byte = kk * 64 + abyteoff;
            short8 a = *(const short8*)(axb + arow * 512 + (byte ^ aswz));
            const short* wp = wbase + (size_t)kk * 2048;
            short8 b0 = *(const short8*)(wp);
            short8 b1 = *(const short8*)(wp + 512);
            short8 b2 = *(const short8*)(wp + 1024);
            short8 b3 = *(const short8*)(wp + 1536);
            acc0 = __builtin_amdgcn_mfma_f32_16x16x32_bf16(a, b0, acc0, 0, 0, 0);
            acc1 = __builtin_amdgcn_mfma_f32_16x16x32_bf16(a, b1, acc1, 0, 0, 0);
            acc2 = __builtin_amdgcn_mfma_f32_16x16x32_bf16(a, b2, acc2, 0, 0, 0);
            acc3 = __builtin_amdgcn_mfma_f32_16x16x32_bf16(a, b3, acc3, 0, 0, 0);
        }
        if (t) {   // h part (t==0: h==0, skip)
            #pragma unroll
            for (int kk = 0; kk < 8; ++kk) {
                int byte = kk * 64 + abyteoff;
                short8 a = *(const short8*)(ahb + arow * 512 + (byte ^ aswz));
                const short* wp = wbase + (size_t)(8 + kk) * 2048;
                short8 b0 = *(const short8*)(wp);
                short8 b1 = *(const short8*)(wp + 512);
                short8 b2 = *(const short8*)(wp + 1024);
                short8 b3 = *(const short8*)(wp + 1536);
                acc0 = __builtin_amdgcn_mfma_f32_16x16x32_bf16(a, b0, acc0, 0, 0, 0);
                acc1 = __builtin_amdgcn_mfma_f32_16x16x32_bf16(a, b1, acc1, 0, 0, 0);
                acc2 = __builtin_amdgcn_mfma_f32_16x16x32_bf16(a, b2, acc2, 0, 0, 0);
                acc3 = __builtin_amdgcn_mfma_f32_16x16x32_bf16(a, b3, acc3, 0, 0, 0);
            }
        }
        // epilogue: gates -> c,h ; h -> Ah[next] (LDS) + enc (global)
        int tl = dir ? (127 - t) : t;
        char* ahw = (char*)Ah[cur ^ 1];
        #pragma unroll
        for (int r = 0; r < 4; ++r) {
            float gi = acc0[r] + bi;
            float gf = acc1[r] + bff;
            float gg = acc2[r] + bg;
            float go = acc3[r] + bo;
            float co = (r == 0) ? c0 : (r == 1) ? c1 : (r == 2) ? c2 : c3;
            float cn = sig_f(gf) * co + sig_f(gi) * tanh_f(gg);
            float h = sig_f(go) * tanh_f(cn);
            if (r == 0) c0 = cn; else if (r == 1) c1 = cn;
            else if (r == 2) c2 = cn; else c3 = cn;
            unsigned short hb = f2b(h);
            int hrow = (lane >> 4) * 4 + r;
            *(unsigned short*)(ahw + hrow * 512 + ((u * 2) ^ ((hrow & 7) << 4))) = hb;
            enc[((size_t)tl * 512 + (s0 + hrow)) * 256 + u] = hb;
        }
        __syncthreads();   // drains gll16 (vmcnt0) + makes Ah[next] visible
    }
}

// ---------------------------------------------------------------------------
// Attention pooling, fully fused per sentence, + sentence-LSTM input
// projection xg. 512 blocks x 256. (unchanged, validated)
// xg layout: xg[dir*8192 + s*16 + unit*4 + gate]
// ---------------------------------------------------------------------------
__global__ __launch_bounds__(256) void k_att(const unsigned short* __restrict__ enc_f,
                                             const unsigned short* __restrict__ enc_b,
                                             const short* __restrict__ attWfrag,
                                             const float* __restrict__ attb,
                                             const float* __restrict__ ctx,
                                             const float* __restrict__ sWih_f,
                                             const float* __restrict__ sWih_b,
                                             float* __restrict__ xg)
{
    __shared__ char encs[128 * 512];   // bf16 [128][256], byte ^= ((l&7)<<4)
    __shared__ float hid[128][129];
    __shared__ float sc[128][5];
    __shared__ float ctxs[4][128];
    __shared__ float attbs[128];
    __shared__ float sentrow[1024];    // sent[d][h] at d*4+h
    int s = blockIdx.x;
    int tid = threadIdx.x;
    int lane = tid & 63, w = tid >> 6;

    if (tid < 128) {
        attbs[tid] = attb[tid];
        #pragma unroll
        for (int h = 0; h < 4; ++h) ctxs[h][tid] = ctx[h * 128 + tid];
    }
    {
        int r = tid >> 1, half = tid & 1;
        const unsigned short* pf_ = enc_f + ((size_t)r * 512 + s) * 256 + half * 128;
        const unsigned short* pb_ = enc_b + ((size_t)r * 512 + s) * 256 + half * 128;
        int st = (r & 7) << 1;
        #pragma unroll
        for (int i = 0; i < 16; ++i) {
            int ii = (i + st) & 15;
            short8 vf = *(const short8*)(pf_ + ii * 8);
            short8 vb = *(const short8*)(pb_ + ii * 8);
            short8 v;
            #pragma unroll
            for (int j = 0; j < 8; ++j)
                v[j] = (short)f2b(b2f((unsigned short)vf[j]) + b2f((unsigned short)vb[j]));
            int byte = half * 256 + ii * 16;
            *(short8*)(encs + r * 512 + (byte ^ ((r & 7) << 4))) = v;
        }
    }
    __syncthreads();

    {
        f32x4 acc[2][8];
        #pragma unroll
        for (int a = 0; a < 2; ++a)
            #pragma unroll
            for (int b = 0; b < 8; ++b) acc[a][b] = (f32x4){0.f, 0.f, 0.f, 0.f};
        int r0 = w * 32 + (lane & 15);
        int r1 = r0 + 16;
        for (int kk = 0; kk < 8; ++kk) {
            int byte = (kk * 32 + (lane >> 4) * 8) * 2;
            short8 a0 = *(const short8*)(encs + r0 * 512 + (byte ^ ((r0 & 7) << 4)));
            short8 a1 = *(const short8*)(encs + r1 * 512 + (byte ^ ((r1 & 7) << 4)));
            #pragma unroll
            for (int nt = 0; nt < 8; ++nt) {
                short8 b = *(const short8*)(attWfrag + ((size_t)(nt * 8 + kk)) * 512 + lane * 8);
                acc[0][nt] = __builtin_amdgcn_mfma_f32_16x16x32_bf16(a0, b, acc[0][nt], 0, 0, 0);
                acc[1][nt] = __builtin_amdgcn_mfma_f32_16x16x32_bf16(a1, b, acc[1][nt], 0, 0, 0);
            }
        }
        #pragma unroll
        for (int mt = 0; mt < 2; ++mt)
            #pragma unroll
            for (int nt = 0; nt < 8; ++nt) {
                int fa = nt * 16 + (lane & 15);
                float ab = attbs[fa];
                #pragma unroll
                for (int r = 0; r < 4; ++r) {
                    int l = w * 32 + mt * 16 + (lane >> 4) * 4 + r;
                    hid[l][fa] = acc[mt][nt][r] + ab;
                }
            }
    }
    __syncthreads();

    {
        int l = tid >> 1;
        int hb = (tid & 1) * 2;
        float d0 = 0.f, d1 = 0.f;
        for (int k = 0; k < 128; ++k) {
            float hv = hid[l][k];
            d0 += hv * ctxs[hb][k];
            d1 += hv * ctxs[hb + 1][k];
        }
        sc[l][hb] = d0;
        sc[l][hb + 1] = d1;
    }
    __syncthreads();

    {
        float v0 = sc[lane][w];
        float v1 = sc[64 + lane][w];
        float m = fmaxf(v0, v1);
        for (int off = 32; off; off >>= 1) m = fmaxf(m, __shfl_xor(m, off));
        float e0 = __expf(v0 - m), e1 = __expf(v1 - m);
        float sm = e0 + e1;
        for (int off = 32; off; off >>= 1) sm += __shfl_xor(sm, off);
        float inv = 1.f / sm;
        sc[lane][w] = e0 * inv;
        sc[64 + lane][w] = e1 * inv;
    }
    __syncthreads();

    {
        int d = tid;
        float a0 = 0.f, a1 = 0.f, a2 = 0.f, a3 = 0.f;
        int byte = d * 2;
        for (int l = 0; l < 128; ++l) {
            float e = b2f(*(const unsigned short*)(encs + l * 512 + (byte ^ ((l & 7) << 4))));
            a0 += e * sc[l][0]; a1 += e * sc[l][1]; a2 += e * sc[l][2]; a3 += e * sc[l][3];
        }
        sentrow[d * 4 + 0] = a0; sentrow[d * 4 + 1] = a1;
        sentrow[d * 4 + 2] = a2; sentrow[d * 4 + 3] = a3;
    }
    __syncthreads();

    {
        int p = tid >> 3;          // 0..31: dir(1) | j(4)
        int sub = tid & 7;
        int dirq = p >> 4, j = p & 15;
        const float* wr = (dirq ? sWih_b : sWih_f) + j * 1024 + sub * 128;
        const float* sr = sentrow + sub * 128;
        float acc = 0.f;
        #pragma unroll
        for (int k = 0; k < 128; k += 4) {
            float4 wv = *(const float4*)(wr + k);
            float4 sv = *(const float4*)(sr + k);
            acc += sv.x * wv.x + sv.y * wv.y + sv.z * wv.z + sv.w * wv.w;
        }
        acc += __shfl_xor(acc, 1);
        acc += __shfl_xor(acc, 2);
        acc += __shfl_xor(acc, 4);
        if (sub == 0)
            xg[dirq * 8192 + s * 16 + (j & 3) * 4 + (j >> 2)] = acc;
    }
}

// ---------------------------------------------------------------------------
// Sentence BiLSTM recurrence (HOP=4). 2 blocks (one per dir) x 64 threads.
// All lanes compute all 4 units redundantly -> NO cross-lane ops in the
// recurrence chain. lane 0 stores h.
// ---------------------------------------------------------------------------
__global__ void k_slstm(const float* __restrict__ xg,
                        const float* __restrict__ sWhh_f, const float* __restrict__ sbih_f,
                        const float* __restrict__ sbhh_f,
                        const float* __restrict__ sWhh_b, const float* __restrict__ sbih_b,
                        const float* __restrict__ sbhh_b,
                        float* __restrict__ hs)
{
    __shared__ float xs[8192];    // [512][16] for this dir
    int dir = blockIdx.x;
    int lane = threadIdx.x;       // 64
    const float* xgd = xg + dir * 8192;
    for (int i = lane; i < 2048; i += 64)
        ((float4*)xs)[i] = ((const float4*)xgd)[i];
    __syncthreads();

    const float* Whh = dir ? sWhh_b : sWhh_f;
    const float* bih = dir ? sbih_b : sbih_f;
    const float* bhh = dir ? sbhh_b : sbhh_f;
    float4 W[16];
    float B[16];
    #pragma unroll
    for (int j = 0; j < 16; ++j) {
        W[j] = *(const float4*)(Whh + j * 4);
        B[j] = bih[j] + bhh[j];
    }
    float* hd = hs + dir * 2048;
    float h0 = 0.f, h1 = 0.f, h2 = 0.f, h3 = 0.f;
    float cA = 0.f, cB = 0.f, cC = 0.f, cD = 0.f;

    for (int tt = 0; tt < 512; ++tt) {
        int idx = dir ? (511 - tt) : tt;
        const float* xv = xs + idx * 16;   // [u*4 + gate]
        float g[16];
        #pragma unroll
        for (int uu = 0; uu < 4; ++uu) {
            #pragma unroll
            for (int gt = 0; gt < 4; ++gt) {
                int j = gt * 4 + uu;
                g[j] = xv[uu * 4 + gt] + B[j]
                     + h0 * W[j].x + h1 * W[j].y + h2 * W[j].z + h3 * W[j].w;
            }
        }
        float i0 = sig_f(g[0]),  i1 = sig_f(g[1]),  i2 = sig_f(g[2]),  i3 = sig_f(g[3]);
        float f0 = sig_f(g[4]),  f1 = sig_f(g[5]),  f2 = sig_f(g[6]),  f3 = sig_f(g[7]);
        float t0 = tanh_f(g[8]), t1 = tanh_f(g[9]), t2 = tanh_f(g[10]), t3 = tanh_f(g[11]);
        float o0 = sig_f(g[12]), o1 = sig_f(g[13]), o2 = sig_f(g[14]), o3 = sig_f(g[15]);
        cA = f0 * cA + i0 * t0; cB = f1 * cB + i1 * t1;
        cC = f2 * cC + i2 * t2; cD = f3 * cD + i3 * t3;
        h0 = o0 * tanh_f(cA); h1 = o1 * tanh_f(cB);
        h2 = o2 * tanh_f(cC); h3 = o3 * tanh_f(cD);
        if (lane == 0) {
            float4 hv = {h0, h1, h2, h3};
            *(float4*)(hd + idx * 4) = hv;
        }
    }
}

// ---------------------------------------------------------------------------
// pf (linear head) + Viterbi, fused. 1 block x 256; pf lives in LDS.
// ---------------------------------------------------------------------------
__global__ void k_vitpf(const float* __restrict__ hs, const float* __restrict__ linW,
                        const float* __restrict__ linb, const float* __restrict__ trans,
                        float* __restrict__ out)
{
    __shared__ float pfs[8192];   // [512][16]
    int tid = threadIdx.x;
    for (int i = tid; i < 8192; i += 256) {
        int s = i >> 4, j = i & 15;
        float acc = linb[j];
        #pragma unroll
        for (int u = 0; u < 4; ++u)
            acc += (hs[s * 4 + u] + hs[2048 + s * 4 + u]) * linW[j * 4 + u];
        pfs[i] = acc;
    }
    __syncthreads();
    if (tid < 64) {
        int j = tid & 15;
        float T[16];
        #pragma unroll
        for (int r = 0; r < 16; ++r) T[r] = trans[((j + r) & 15) * 16 + j];
        float v = pfs[j];
        if (tid < 16) out[j] = v;
        for (int t = 1; t < 512; ++t) {
            float m = -1e30f;
            #pragma unroll
            for (int r = 0; r < 16; ++r) {
                float vv = __shfl(v, (j + r) & 15);
                m = fmaxf(m, vv + T[r]);
            }
            v = pfs[t * 16 + j] + m;
            if (tid < 16) out[t * 16 + j] = v;
        }
    }
}

// ---------------------------------------------------------------------------
extern "C" void kernel_launch(void* const* d_in, const int* in_sizes, int n_in,
                              void* d_out, int out_size, void* d_ws, size_t ws_size,
                              hipStream_t stream) {
    (void)in_sizes; (void)n_in; (void)out_size; (void)ws_size;
    const int*   tokens = (const int*)d_in[0];
    const float* emb    = (const float*)d_in[1];
    const float* tWih_f = (const float*)d_in[2];
    const float* tWhh_f = (const float*)d_in[3];
    const float* tbih_f = (const float*)d_in[4];
    const float* tbhh_f = (const float*)d_in[5];
    const float* tWih_b = (const float*)d_in[6];
    const float* tWhh_b = (const float*)d_in[7];
    const float* tbih_b = (const float*)d_in[8];
    const float* tbhh_b = (const float*)d_in[9];
    const float* attW   = (const float*)d_in[10];
    const float* attb   = (const float*)d_in[11];
    const float* ctx    = (const float*)d_in[12];
    const float* sWih_f = (const float*)d_in[13];
    const float* sWhh_f = (const float*)d_in[14];
    const float* sbih_f = (const float*)d_in[15];
    const float* sbhh_f = (const float*)d_in[16];
    const float* sWih_b = (const float*)d_in[17];
    const float* sWhh_b = (const float*)d_in[18];
    const float* sbih_b = (const float*)d_in[19];
    const float* sbhh_b = (const float*)d_in[20];
    const float* linW   = (const float*)d_in[21];
    const float* linb   = (const float*)d_in[22];
    const float* trans  = (const float*)d_in[23];

    char* ws = (char*)d_ws;
    size_t off = 0;
    auto alloc = [&](size_t bytes) -> void* {
        void* p = ws + off;
        off += (bytes + 255) & ~(size_t)255;
        return p;
    };
    short* Wfrag            = (short*)alloc((size_t)2 * 1024 * 512 * 2);
    float* biasp            = (float*)alloc(2048 * 4);
    short* attWfrag         = (short*)alloc(32768 * 2);
    unsigned short* emb16   = (unsigned short*)alloc((size_t)50000 * 256 * 2);
    unsigned short* enc_f   = (unsigned short*)alloc((size_t)128 * 512 * 256 * 2);
    unsigned short* enc_b   = (unsigned short*)alloc((size_t)128 * 512 * 256 * 2);
    float* xg               = (float*)alloc(16384 * 4);
    float* hs               = (float*)alloc(4096 * 4);

    int prep_total = 2 * 1024 * 512 + 2048 + 32768;
    k_prep<<<(prep_total + 255) / 256, 256, 0, stream>>>(
        tWih_f, tWhh_f, tbih_f, tbhh_f, tWih_b, tWhh_b, tbih_b, tbhh_b,
        attW, Wfrag, biasp, attWfrag);
    k_prep_emb<<<(50000 * 256 / 8 + 255) / 256, 256, 0, stream>>>(emb, emb16);

    k_tokf<<<64, 1024, 0, stream>>>(tokens, emb16, Wfrag, biasp, enc_f, enc_b);

    k_att<<<512, 256, 0, stream>>>(enc_f, enc_b, attWfrag, attb, ctx,
                                   sWih_f, sWih_b, xg);
    k_slstm<<<2, 64, 0, stream>>>(xg, sWhh_f, sbih_f, sbhh_f,
                                  sWhh_b, sbih_b, sbhh_b, hs);
    k_vitpf<<<1, 256, 0, stream>>>(hs, linW, linb, trans, (float*)d_out);
}